// Round 10
// baseline (565.059 us; speedup 1.0000x reference)
//
#include <hip/hip_runtime.h>
#include <hip/hip_bf16.h>
#include <stdint.h>

typedef __attribute__((ext_vector_type(8))) short short8;
typedef __attribute__((ext_vector_type(4))) float f32x4;

#define AS1 __attribute__((address_space(1)))
#define AS3 __attribute__((address_space(3)))

// RNE float->bf16 (inputs are finite; no NaN handling needed)
static __device__ __forceinline__ unsigned short f2bf(float f) {
    unsigned int u = __float_as_uint(f);
    u += 0x7FFFu + ((u >> 16) & 1u);
    return (unsigned short)(u >> 16);
}

__global__ void init_amax(unsigned int* amax) {
    if (threadIdx.x < 2) amax[threadIdx.x] = 0u;
}

__global__ void absmax_kernel(const float4* __restrict__ w, size_t n4,
                              unsigned int* __restrict__ out) {
    float m = 0.0f;
    size_t i = (size_t)blockIdx.x * blockDim.x + threadIdx.x;
    size_t stride = (size_t)gridDim.x * blockDim.x;
    for (; i < n4; i += stride) {
        float4 v = w[i];
        m = fmaxf(m, fmaxf(fmaxf(fabsf(v.x), fabsf(v.y)),
                           fmaxf(fabsf(v.z), fabsf(v.w))));
    }
    #pragma unroll
    for (int off = 32; off > 0; off >>= 1)
        m = fmaxf(m, __shfl_down(m, off, 64));
    __shared__ float sm[4];
    int lane = threadIdx.x & 63, wid = threadIdx.x >> 6;
    if (lane == 0) sm[wid] = m;
    __syncthreads();
    if (threadIdx.x == 0) {
        float bm = fmaxf(fmaxf(sm[0], sm[1]), fmaxf(sm[2], sm[3]));
        atomicMax(out, __float_as_uint(bm));  // floats >=0: uint bit-compare monotone
    }
}

// FP4 E2M1 quantize to exact bf16 grid value (scale kept separate).
// idx = sum(a > mids[j]) matches np.searchsorted(mids, a, side='left').
static __device__ __forceinline__ unsigned short quant_one(float wv, float scale) {
    float a = fabsf(wv) / scale;
    int idx = (a > 0.25f) + (a > 0.75f) + (a > 1.25f) + (a > 1.75f)
            + (a > 2.5f)  + (a > 3.5f)  + (a > 5.0f);
    const unsigned long long lo = 0x3FC03F803F000000ull;  // bf16 bits {0,.5,1,1.5}
    const unsigned long long hi = 0x40C0408040404000ull;  // bf16 bits {2,3,4,6}
    unsigned long long tab = (idx < 4) ? lo : hi;
    unsigned short mag = (unsigned short)(tab >> ((idx & 3) * 16));
    unsigned short sgn = (unsigned short)((__float_as_uint(wv) >> 16) & 0x8000u);
    return (unsigned short)(mag | sgn);
}

__global__ void quant_kernel(const float4* __restrict__ w, size_t n4,
                             const unsigned int* __restrict__ amax,
                             ushort4* __restrict__ q) {
    const float scale = __uint_as_float(*amax) / 6.0f;
    size_t i = (size_t)blockIdx.x * blockDim.x + threadIdx.x;
    size_t stride = (size_t)gridDim.x * blockDim.x;
    for (; i < n4; i += stride) {
        float4 v = w[i];
        ushort4 o;
        o.x = quant_one(v.x, scale);
        o.y = quant_one(v.y, scale);
        o.z = quant_one(v.z, scale);
        o.w = quant_one(v.w, scale);
        q[i] = o;
    }
}

__global__ void cast_bf16_kernel(const float4* __restrict__ x, size_t n4,
                                 ushort4* __restrict__ o) {
    size_t i = (size_t)blockIdx.x * blockDim.x + threadIdx.x;
    size_t stride = (size_t)gridDim.x * blockDim.x;
    for (; i < n4; i += stride) {
        float4 v = x[i];
        ushort4 r;
        r.x = f2bf(v.x); r.y = f2bf(v.y); r.z = f2bf(v.z); r.w = f2bf(v.w);
        o[i] = r;
    }
}

// ====== 256x128 GEMM, BK=32, 256 thr, 48KiB LDS -> 2 independent blocks/CU ======
// C[M][N] = A[M][K] (bf16) * B[N][K]^T (bf16), f32 acc.
// 4 waves (2M x 2N), wave tile 128x64 -> acc[8][4] f32x4 (128 AGPR).
// The two co-resident blocks have NO shared barriers -> one block's MFMA covers
// the other's ds_read bursts and vmcnt(0) drains (m97/m114 mechanism).
// LDS: 2 bufs x 24KB @ {0, 24576}; per buf: A 16KB (16 subtiles) | B 8KB (8).
// Subtile = 16 rows x 32 k (1024B); byte = swz(rin*64 + kin*2),
// swz(x) = x ^ (((x>>9)&1)<<5). global_load_lds dest LINEAR; global source
// carries the inverse swizzle (both-sides rule, verified R6/R9).
// Per step: STAGE next (6 loads) -> 12 ds_reads (B then A) -> lgkm(4) ->
// 16 MFMA -> lgkm(0) -> 16 MFMA -> vmcnt(0) -> BAR.
// LAYA=1: A is H'-blocked (written by GEMM1): f(row,k) = (row>>4)*262144 +
// (k>>4)*512 + (row&3)*128 + ((row>>2)&3)*32 + (k&15)*2  (262144 = 16*8192*2).

#define GLL(gp, dst)                                                    \
    __builtin_amdgcn_global_load_lds((const AS1 unsigned int*)(gp),     \
        (AS3 unsigned int*)(dst), 16, 0, 0)

#define STAGE(bufw, sA, sB)                                             \
    do {                                                                \
        GLL(pA + (sA) + goffA0, lds + (bufw) + tid * 16);               \
        GLL(pA + (sA) + goffA1, lds + (bufw) + 4096 + tid * 16);        \
        GLL(pA + (sA) + goffA2, lds + (bufw) + 8192 + tid * 16);        \
        GLL(pA + (sA) + goffA3, lds + (bufw) + 12288 + tid * 16);       \
        GLL(pB + (sB) + goffB0, lds + (bufw) + 16384 + tid * 16);       \
        GLL(pB + (sB) + goffB1, lds + (bufw) + 20480 + tid * 16);       \
    } while (0)

#define RD_B(bufr)                                                      \
    do {                                                                \
        _Pragma("unroll") for (int _j = 0; _j < 4; ++_j)                \
            b_[_j] = *(const short8*)(ldsB + (bufr) + _j * 1024);       \
    } while (0)

#define RD_A(bufr)                                                      \
    do {                                                                \
        _Pragma("unroll") for (int _i = 0; _i < 8; ++_i)                \
            a_[_i] = *(const short8*)(ldsA + (bufr) + _i * 1024);       \
    } while (0)

#define MF4(I0)                                                                \
    do {                                                                       \
        _Pragma("unroll") for (int _i = 0; _i < 4; ++_i)                       \
            _Pragma("unroll") for (int _j = 0; _j < 4; ++_j)                   \
                acc[(I0) + _i][_j] = __builtin_amdgcn_mfma_f32_16x16x32_bf16(  \
                    a_[(I0) + _i], b_[_j], acc[(I0) + _i][_j], 0, 0, 0);       \
    } while (0)

#define BAR()  __builtin_amdgcn_s_barrier()
#define SCHB() __builtin_amdgcn_sched_barrier(0)
#define LGKM(n) do { SCHB(); asm volatile("s_waitcnt lgkmcnt(" #n ")"); SCHB(); } while (0)

template <int RELU_BF16, int LAYA>
__global__ __launch_bounds__(256, 2)
void gemmT(const char* __restrict__ A,          // LAYA=0: row-major bf16; 1: H'-blocked
           const unsigned short* __restrict__ B,
           const float* __restrict__ bias,
           const unsigned int* __restrict__ amax,
           float* __restrict__ outF,            // RELU_BF16=0 dest (row-major f32)
           char* __restrict__ outH,             // RELU_BF16=1 dest (H'-blocked bf16)
           int N, int K, int gx, int cw, int NK) {
    __shared__ __align__(16) char lds[49152];

    const int tid  = threadIdx.x;
    const int lane = tid & 63;
    const int wid  = tid >> 6;
    const int wm   = wid >> 1;   // 0..1: 128-row half
    const int wn   = wid & 1;    // 0..1: 64-col slice

    // 2D-chunked XCD mapping
    const int nwg = gridDim.x;
    const int wg  = blockIdx.x;
    const int c   = wg & 7;
    const int idx = wg >> 3;
    const int nc  = nwg >> 3;
    const int cxc = gx / cw;
    const int ox  = (c % cxc) * cw;
    const int oy  = (c / cxc) * (nc / cw);
    const int bx  = ox + idx % cw;
    const int by  = oy + idx / cw;
    const int col0 = bx * 128;
    const int row0 = by * 256;

    // per-lane swizzled fragment offset within a 1024B subtile
    int sp = ((lane & 15) << 6) + ((lane >> 4) << 4);
    sp ^= ((sp >> 9) & 1) << 5;
    const char* ldsA = lds + wm * 8192 + sp;          // + bufr, + i*1024
    const char* ldsB = lds + 16384 + wn * 4096 + sp;  // + bufr, + j*1024

    // stage source byte-offsets: LDS linear dest o holds element (row,k)=unswz(o)
    int goffA0, goffA1, goffA2, goffA3, goffB0, goffB1;
    {
        #pragma unroll
        for (int j = 0; j < 4; ++j) {
            int o = j * 4096 + tid * 16;
            int st = o >> 10, b = o & 1023;
            b ^= ((b >> 9) & 1) << 5;
            int row = (st << 4) + (b >> 6);
            int k   = (b & 63) >> 1;
            int g = LAYA ? ((row >> 4) * 262144 + (k >> 4) * 512 +
                            (row & 3) * 128 + ((row >> 2) & 3) * 32 + (k & 15) * 2)
                         : (row * K + k) * 2;
            if (j == 0) goffA0 = g; else if (j == 1) goffA1 = g;
            else if (j == 2) goffA2 = g; else goffA3 = g;
        }
        #pragma unroll
        for (int j = 0; j < 2; ++j) {
            int o = j * 4096 + tid * 16;
            int st = o >> 10, b = o & 1023;
            b ^= ((b >> 9) & 1) << 5;
            int col = (st << 4) + (b >> 6);
            int k   = (b & 63) >> 1;
            int g = (col * K + k) * 2;
            if (j == 0) goffB0 = g; else goffB1 = g;
        }
    }
    const char* pA = A + (LAYA ? (size_t)(row0 >> 4) * 262144 : (size_t)row0 * K * 2);
    const char* pB = (const char*)B + (size_t)col0 * K * 2;
    const size_t dA = LAYA ? 1024 : 64;   // byte advance per K-step (32 elems)

    // prologue: stage step 0 -> buf0
    STAGE(0, 0, 0);
    asm volatile("s_waitcnt vmcnt(0)");
    BAR();

    f32x4 acc[8][4] = {};
    short8 a_[8], b_[4];

    for (int s = 0; s < NK - 1; ++s) {
        const int bufr = (s & 1) * 24576;
        const int bufw = bufr ^ 24576;
        STAGE(bufw, (size_t)(s + 1) * dA, (size_t)(s + 1) * 64);
        RD_B(bufr); RD_A(bufr);
        LGKM(4);                 // B(4) + A0..3 retired; A4..7 in flight
        MF4(0);
        LGKM(0);
        MF4(4);
        asm volatile("s_waitcnt vmcnt(0)");   // next buf staged (other block covers)
        BAR();
    }
    {
        const int bufr = ((NK - 1) & 1) * 24576;
        RD_B(bufr); RD_A(bufr);
        LGKM(4);
        MF4(0);
        LGKM(0);
        MF4(4);
        BAR();   // protect LDS reuse by f32 epilogue
    }

    // acc C/D layout (verified m89/m91): col = lane&15, row = (lane>>4)*4 + r
    const float scale = __uint_as_float(*amax) / 6.0f;

    if (RELU_BF16) {
        // H'-blocked store: 64 lanes x 2B cover 128B contiguous per (j,i,r)
        const int gbit = (lane >> 4) * 32 + (lane & 15) * 2;
        #pragma unroll
        for (int j = 0; j < 4; ++j) {
            const int col = col0 + wn * 64 + j * 16 + (lane & 15);
            const float bvv = bias[col];
            const size_t ktb = (size_t)(((col0 + wn * 64) >> 4) + j) * 512;
            #pragma unroll
            for (int i = 0; i < 8; ++i) {
                const size_t rtb = (size_t)(((row0 + wm * 128) >> 4) + i) * 262144;
                #pragma unroll
                for (int r = 0; r < 4; ++r) {
                    float v = fmaxf(acc[i][j][r] * scale + bvv, 0.0f);
                    *(unsigned short*)(outH + rtb + ktb + r * 128 + gbit) = f2bf(v);
                }
            }
        }
    } else {
        // f32 out via LDS: 4 passes of 64 rows x 128 cols (32KB);
        // 16B-block XOR swizzle keyed on (row_l>>2)&3 -> 2-way max on writes
        #pragma unroll
        for (int p = 0; p < 4; ++p) {
            if (wm == (p >> 1)) {
                const int h = p & 1;
                #pragma unroll
                for (int j = 0; j < 4; ++j) {
                    const int colb = wn * 64 + j * 16 + (lane & 15);
                    const float bvv = bias[col0 + colb];
                    #pragma unroll
                    for (int ii = 0; ii < 4; ++ii) {
                        const int i = h * 4 + ii;
                        #pragma unroll
                        for (int r = 0; r < 4; ++r) {
                            const int row_l = ii * 16 + (lane >> 4) * 4 + r;
                            const int blk = (colb >> 2) ^ (((row_l >> 2) & 3) << 2);
                            *(float*)(lds + row_l * 512 + blk * 16 + (colb & 3) * 4)
                                = acc[i][j][r] * scale + bvv;
                        }
                    }
                }
            }
            asm volatile("s_waitcnt lgkmcnt(0)");
            BAR();
            #pragma unroll
            for (int q = 0; q < 8; ++q) {
                const int flat  = q * 4096 + tid * 16;
                const int row_l = flat >> 9;
                const int blk0  = (flat >> 4) & 31;
                const int blk   = blk0 ^ (((row_l >> 2) & 3) << 2);
                f32x4 v = *(const f32x4*)(lds + row_l * 512 + blk * 16);
                *(f32x4*)(outF + (size_t)(row0 + p * 64 + row_l) * N
                                 + col0 + blk0 * 4) = v;
            }
            BAR();
        }
    }
}

extern "C" void kernel_launch(void* const* d_in, const int* in_sizes, int n_in,
                              void* d_out, int out_size, void* d_ws, size_t ws_size,
                              hipStream_t stream) {
    const float* x  = (const float*)d_in[0];   // [8192, 2048]
    const float* W1 = (const float*)d_in[1];   // [8192, 2048]
    const float* b1 = (const float*)d_in[2];   // [8192]
    const float* W2 = (const float*)d_in[3];   // [2048, 8192]
    const float* b2 = (const float*)d_in[4];   // [2048]
    float* out = (float*)d_out;                // [8192, 2048] f32

    const int Bm = 8192, Din = 2048, Dh = 8192, Dout = 2048;
    const size_t nW1 = (size_t)Dh * Din;
    const size_t nW2 = (size_t)Dout * Dh;
    const size_t nX  = (size_t)Bm * Din;
    const size_t nH  = (size_t)Bm * Dh;

    const size_t need = 256 + 2 * (nW1 + nW2 + nX + nH);
    if (ws_size < need) return;

    uint8_t* ws = (uint8_t*)d_ws;
    unsigned int*   amax = (unsigned int*)ws;
    unsigned short* Q1 = (unsigned short*)(ws + 256);
    unsigned short* Q2 = Q1 + nW1;
    unsigned short* Xb = Q2 + nW2;
    char*           H  = (char*)(Xb + nX);     // H'-blocked bf16, nH*2 bytes

    init_amax<<<1, 64, 0, stream>>>(amax);
    absmax_kernel<<<1024, 256, 0, stream>>>((const float4*)W1, nW1 / 4, amax + 0);
    absmax_kernel<<<1024, 256, 0, stream>>>((const float4*)W2, nW2 / 4, amax + 1);
    quant_kernel<<<2048, 256, 0, stream>>>((const float4*)W1, nW1 / 4, amax + 0, (ushort4*)Q1);
    quant_kernel<<<2048, 256, 0, stream>>>((const float4*)W2, nW2 / 4, amax + 1, (ushort4*)Q2);
    cast_bf16_kernel<<<2048, 256, 0, stream>>>((const float4*)x, nX / 4, (ushort4*)Xb);

    // h = relu(scale1 * (x @ Q1^T) + b1) -> H'-blocked bf16
    // grid 64 x 32 = 2048 blocks -> 8 per CU (4 rounds of 2)
    gemmT<1, 0><<<dim3(2048), 256, 0, stream>>>(
        (const char*)Xb, Q1, b1, amax + 0, nullptr, H,
        /*N=*/Dh, /*K=*/Din, /*gx=*/Dh / 128, /*cw=*/16, /*NK=*/Din / 32);
    // y = scale2 * (h @ Q2^T) + b2 -> f32 row-major
    // grid 16 x 32 = 512 blocks -> exactly 2 per CU
    gemmT<0, 1><<<dim3(512), 256, 0, stream>>>(
        H, Q2, b2, amax + 1, out, nullptr,
        /*N=*/Dout, /*K=*/Dh, /*gx=*/Dout / 128, /*cw=*/16, /*NK=*/Dh / 32);
}

// Round 11
// 560.257 us; speedup vs baseline: 1.0086x; 1.0086x over previous
//
#include <hip/hip_runtime.h>
#include <hip/hip_bf16.h>
#include <stdint.h>

typedef __attribute__((ext_vector_type(8))) short short8;
typedef __attribute__((ext_vector_type(4))) float f32x4;

#define AS1 __attribute__((address_space(1)))
#define AS3 __attribute__((address_space(3)))

// RNE float->bf16 (inputs are finite; no NaN handling needed)
static __device__ __forceinline__ unsigned short f2bf(float f) {
    unsigned int u = __float_as_uint(f);
    u += 0x7FFFu + ((u >> 16) & 1u);
    return (unsigned short)(u >> 16);
}

__global__ void init_amax(unsigned int* amax) {
    if (threadIdx.x < 2) amax[threadIdx.x] = 0u;
}

__global__ void absmax_kernel(const float4* __restrict__ w, size_t n4,
                              unsigned int* __restrict__ out) {
    float m = 0.0f;
    size_t i = (size_t)blockIdx.x * blockDim.x + threadIdx.x;
    size_t stride = (size_t)gridDim.x * blockDim.x;
    for (; i < n4; i += stride) {
        float4 v = w[i];
        m = fmaxf(m, fmaxf(fmaxf(fabsf(v.x), fabsf(v.y)),
                           fmaxf(fabsf(v.z), fabsf(v.w))));
    }
    #pragma unroll
    for (int off = 32; off > 0; off >>= 1)
        m = fmaxf(m, __shfl_down(m, off, 64));
    __shared__ float sm[4];
    int lane = threadIdx.x & 63, wid = threadIdx.x >> 6;
    if (lane == 0) sm[wid] = m;
    __syncthreads();
    if (threadIdx.x == 0) {
        float bm = fmaxf(fmaxf(sm[0], sm[1]), fmaxf(sm[2], sm[3]));
        atomicMax(out, __float_as_uint(bm));  // floats >=0: uint bit-compare monotone
    }
}

// FP4 E2M1 quantize to exact bf16 grid value (scale kept separate).
// idx = sum(a > mids[j]) matches np.searchsorted(mids, a, side='left').
static __device__ __forceinline__ unsigned short quant_one(float wv, float scale) {
    float a = fabsf(wv) / scale;
    int idx = (a > 0.25f) + (a > 0.75f) + (a > 1.25f) + (a > 1.75f)
            + (a > 2.5f)  + (a > 3.5f)  + (a > 5.0f);
    const unsigned long long lo = 0x3FC03F803F000000ull;  // bf16 bits {0,.5,1,1.5}
    const unsigned long long hi = 0x40C0408040404000ull;  // bf16 bits {2,3,4,6}
    unsigned long long tab = (idx < 4) ? lo : hi;
    unsigned short mag = (unsigned short)(tab >> ((idx & 3) * 16));
    unsigned short sgn = (unsigned short)((__float_as_uint(wv) >> 16) & 0x8000u);
    return (unsigned short)(mag | sgn);
}

__global__ void quant_kernel(const float4* __restrict__ w, size_t n4,
                             const unsigned int* __restrict__ amax,
                             ushort4* __restrict__ q) {
    const float scale = __uint_as_float(*amax) / 6.0f;
    size_t i = (size_t)blockIdx.x * blockDim.x + threadIdx.x;
    size_t stride = (size_t)gridDim.x * blockDim.x;
    for (; i < n4; i += stride) {
        float4 v = w[i];
        ushort4 o;
        o.x = quant_one(v.x, scale);
        o.y = quant_one(v.y, scale);
        o.z = quant_one(v.z, scale);
        o.w = quant_one(v.w, scale);
        q[i] = o;
    }
}

__global__ void cast_bf16_kernel(const float4* __restrict__ x, size_t n4,
                                 ushort4* __restrict__ o) {
    size_t i = (size_t)blockIdx.x * blockDim.x + threadIdx.x;
    size_t stride = (size_t)gridDim.x * blockDim.x;
    for (; i < n4; i += stride) {
        float4 v = x[i];
        ushort4 r;
        r.x = f2bf(v.x); r.y = f2bf(v.y); r.z = f2bf(v.z); r.w = f2bf(v.w);
        o[i] = r;
    }
}

// ===== 256x256 GEMM, BK=32, 3-deep LDS buffers, 1 barrier/tile (R9 machinery) =====
// C[M][N] = A[M][K] (bf16) * B[N][K]^T (bf16), f32 acc.
// 512 thr = 8 waves (2M x 4N), wave tile 128x64, acc[8][4] f32x4.
// LDS 96KiB = 3 bufs x 32KB (tile t -> buf t%3); per buf:
//   A rows 0-127 @ +0 (8KB), A rows 128-255 @ +8192, B cols 0-127 @ +16384,
//   B cols 128-255 @ +24576. Subtile = 16 rows x 32 k (1024B);
//   byte = swz(rin*64 + kin*2), swz(x) = x ^ (((x>>9)&1)<<5).
// global_load_lds dest LINEAR; global source carries inverse swizzle (R6/R9-verified).
//
// Per tile T: [stage T+2 -> buf(T+2)%3 = buf(T-1)%3, 4 GLL] -> 12 ds_reads
// (b 4, aP 4, aQ 4) -> lgkm(4) -> 16 MFMA (aP) -> lgkm(0) -> 16 MFMA (aQ)
// -> vmcnt(4) -> BAR.  No mid-tile drain barrier: buf(T-1) reads were fenced
// by the T-1 boundary barrier (each wave's lgkm(0) precedes it).
// vmcnt ledger (induction): enter tile with 8 outstanding (T+1's 4 staged in
// T-1, T+2's 4 just issued); vmcnt(4) retires exactly T+1's 4.
// Penultimate tile: vmcnt(0). Prologue: stage tiles 0,1; vmcnt(4).
// LAYA=1: A is H'-blocked (written by GEMM1): f(row,k) = (row>>4)*262144 +
// (k>>4)*512 + (row&3)*128 + ((row>>2)&3)*32 + (k&15)*2.

#define GLL(gp, dst)                                                    \
    __builtin_amdgcn_global_load_lds((const AS1 unsigned int*)(gp),     \
        (AS3 unsigned int*)(dst), 16, 0, 0)

// stage tile kt (index) into buffer at byte offset bufw: 4 loads of 8KB
#define STAGE_T(kt, bufw)                                                     \
    do {                                                                      \
        GLL(pA0 + (size_t)(kt) * dA + goffA, lds + (bufw) + tid * 16);        \
        GLL(pA1 + (size_t)(kt) * dA + goffA, lds + (bufw) + 8192 + tid * 16); \
        GLL(pB0 + (size_t)(kt) * 64 + goffB, lds + (bufw) + 16384 + tid * 16);\
        GLL(pB1 + (size_t)(kt) * 64 + goffB, lds + (bufw) + 24576 + tid * 16);\
    } while (0)

#define RDB(bo)                                                         \
    do {                                                                \
        _Pragma("unroll") for (int _j = 0; _j < 4; ++_j)                \
            b_[_j] = *(const short8*)(ldsB + (bo) + _j * 1024);         \
    } while (0)

#define RDA(bo, dst, s0)                                                \
    do {                                                                \
        _Pragma("unroll") for (int _i = 0; _i < 4; ++_i)                \
            dst[_i] = *(const short8*)(ldsA + (bo) + ((s0) + _i) * 1024);\
    } while (0)

// 16 MFMA: acc[I0+i][j] += ARR[i] * b_[j]
#define MFG16(I0, ARR)                                                         \
    do {                                                                       \
        _Pragma("unroll") for (int _i = 0; _i < 4; ++_i)                       \
            _Pragma("unroll") for (int _j = 0; _j < 4; ++_j)                   \
                acc[(I0) + _i][_j] = __builtin_amdgcn_mfma_f32_16x16x32_bf16(  \
                    ARR[_i], b_[_j], acc[(I0) + _i][_j], 0, 0, 0);             \
    } while (0)

#define BAR()  __builtin_amdgcn_s_barrier()
#define PRIO(x) __builtin_amdgcn_s_setprio(x)
#define SCHB() __builtin_amdgcn_sched_barrier(0)
#define LGKM(n) do { SCHB(); asm volatile("s_waitcnt lgkmcnt(" #n ")"); SCHB(); } while (0)

template <int RELU_BF16, int LAYA>
__global__ __launch_bounds__(512, 2)
void gemm3(const char* __restrict__ A,          // LAYA=0: row-major bf16; 1: H'-blocked
           const unsigned short* __restrict__ B,
           const float* __restrict__ bias,
           const unsigned int* __restrict__ amax,
           float* __restrict__ outF,            // RELU_BF16=0 dest (row-major f32)
           char* __restrict__ outH,             // RELU_BF16=1 dest (H'-blocked bf16)
           int N, int K, int gx, int cw, int NT) {
    __shared__ __align__(16) char lds[98304];

    const int tid  = threadIdx.x;
    const int lane = tid & 63;
    const int wid  = tid >> 6;
    const int wm   = wid >> 2;   // 0..1: 128-row half
    const int wn   = wid & 3;    // 0..3: 64-col slice

    // 2D-chunked XCD mapping (R9-verified)
    const int nwg = gridDim.x;
    const int wg  = blockIdx.x;
    const int c   = wg & 7;
    const int idx = wg >> 3;
    const int nc  = nwg >> 3;
    const int cxc = gx / cw;
    const int ox  = (c % cxc) * cw;
    const int oy  = (c / cxc) * (nc / cw);
    const int bx  = ox + idx % cw;
    const int by  = oy + idx / cw;
    const int col0 = bx * 256;
    const int row0 = by * 256;

    // per-lane swizzled fragment offset within a 1024B subtile
    int sp = ((lane & 15) << 6) + ((lane >> 4) << 4);
    sp ^= ((sp >> 9) & 1) << 5;
    const char* ldsA = lds + wm * 8192 + sp;                          // + buf, + i*1024
    const char* ldsB = lds + 16384 + (wn >> 1) * 8192 + (wn & 1) * 4096 + sp;

    // stage source byte-offset: LDS linear dest o = tid*16 holds (row,k)=unswz(o)
    int goffA, goffB;
    {
        int o = tid * 16;
        int s = o >> 10, b = o & 1023;
        b ^= ((b >> 9) & 1) << 5;
        int row = (s << 4) + (b >> 6);
        int k   = (b & 63) >> 1;
        goffA = LAYA ? ((row >> 4) * 262144 + (k >> 4) * 512 +
                        (row & 3) * 128 + ((row >> 2) & 3) * 32 + (k & 15) * 2)
                     : (row * K + k) * 2;
        goffB = (row * K + k) * 2;
    }
    const char* pA0 = A + (LAYA ? (size_t)row0 * 16384 : (size_t)row0 * K * 2);
    const char* pA1 = A + (LAYA ? (size_t)(row0 + 128) * 16384
                                : (size_t)(row0 + 128) * K * 2);
    const char* pB0 = (const char*)B + (size_t)col0 * K * 2;
    const char* pB1 = (const char*)B + (size_t)(col0 + 128) * K * 2;
    const size_t dA = LAYA ? 1024 : 64;   // A byte advance per tile (32 k-elems)

    // prologue: tiles 0,1 -> bufs 0,1
    STAGE_T(0, 0);
    STAGE_T(1, 32768);
    asm volatile("s_waitcnt vmcnt(4)");   // tile0 landed
    BAR();

    f32x4 acc[8][4] = {};
    short8 aP[4], aQ[4], b_[4];
    int oc = 0, on = 32768, o2 = 65536;

    for (int t = 0; t < NT; ++t) {
        if (t + 2 < NT) STAGE_T(t + 2, o2);
        RDB(oc);            // B: 4 reads (issued first)
        RDA(oc, aP, 0);     // A subtiles 0..3
        RDA(oc, aQ, 4);     // A subtiles 4..7
        LGKM(4);            // b + aP retired (oldest 8 of 12); aQ in flight
        PRIO(1); MFG16(0, aP); PRIO(0);
        LGKM(0);            // aQ retired
        PRIO(1); MFG16(4, aQ); PRIO(0);
        if (t + 2 < NT)      { asm volatile("s_waitcnt vmcnt(4)"); }
        else if (t + 1 < NT) { asm volatile("s_waitcnt vmcnt(0)"); }
        BAR();
        int tmp = oc; oc = on; on = o2; o2 = tmp;
    }

    // acc C/D layout (verified m89/m91): col = lane&15, row = (lane>>4)*4 + r
    const float scale = __uint_as_float(*amax) / 6.0f;

    if (RELU_BF16) {
        // H'-blocked store: 64 lanes x 2B cover 128B contiguous per (j,i,r)
        const int gbit = (lane >> 4) * 32 + (lane & 15) * 2;
        #pragma unroll
        for (int j = 0; j < 4; ++j) {
            const int col = col0 + wn * 64 + j * 16 + (lane & 15);
            const float bvv = bias[col];
            const size_t ktb = (size_t)(((col0 + wn * 64) >> 4) + j) * 512;
            #pragma unroll
            for (int i = 0; i < 8; ++i) {
                const size_t rtb = (size_t)(((row0 + wm * 128) >> 4) + i) * 262144;
                #pragma unroll
                for (int r = 0; r < 4; ++r) {
                    float v = fmaxf(acc[i][j][r] * scale + bvv, 0.0f);
                    *(unsigned short*)(outH + rtb + ktb + r * 128 + gbit) = f2bf(v);
                }
            }
        }
    } else {
        // f32 out via LDS: 4 passes of 64 rows x 256 cols (64KB);
        // 16B-block XOR swizzle keyed on (row_l>>2)&3
        #pragma unroll
        for (int p = 0; p < 4; ++p) {
            if (wm == (p >> 1)) {
                const int h = p & 1;
                #pragma unroll
                for (int j = 0; j < 4; ++j) {
                    const int colb = wn * 64 + j * 16 + (lane & 15);
                    const float bvv = bias[col0 + colb];
                    #pragma unroll
                    for (int ii = 0; ii < 4; ++ii) {
                        const int i = h * 4 + ii;
                        #pragma unroll
                        for (int r = 0; r < 4; ++r) {
                            const int row_l = ii * 16 + (lane >> 4) * 4 + r;
                            const int blk = (colb >> 2) ^ (((row_l >> 2) & 3) << 2);
                            *(float*)(lds + row_l * 1024 + blk * 16 + (colb & 3) * 4)
                                = acc[i][j][r] * scale + bvv;
                        }
                    }
                }
            }
            asm volatile("s_waitcnt lgkmcnt(0)");
            BAR();
            #pragma unroll
            for (int q = 0; q < 8; ++q) {
                const int flat  = q * 8192 + tid * 16;
                const int row_l = flat >> 10;
                const int blk0  = (flat >> 4) & 63;
                const int blk   = blk0 ^ (((row_l >> 2) & 3) << 2);
                f32x4 v = *(const f32x4*)(lds + row_l * 1024 + blk * 16);
                *(f32x4*)(outF + (size_t)(row0 + p * 64 + row_l) * N
                                 + col0 + blk0 * 4) = v;
            }
            BAR();
        }
    }
}

extern "C" void kernel_launch(void* const* d_in, const int* in_sizes, int n_in,
                              void* d_out, int out_size, void* d_ws, size_t ws_size,
                              hipStream_t stream) {
    const float* x  = (const float*)d_in[0];   // [8192, 2048]
    const float* W1 = (const float*)d_in[1];   // [8192, 2048]
    const float* b1 = (const float*)d_in[2];   // [8192]
    const float* W2 = (const float*)d_in[3];   // [2048, 8192]
    const float* b2 = (const float*)d_in[4];   // [2048]
    float* out = (float*)d_out;                // [8192, 2048] f32

    const int Bm = 8192, Din = 2048, Dh = 8192, Dout = 2048;
    const size_t nW1 = (size_t)Dh * Din;
    const size_t nW2 = (size_t)Dout * Dh;
    const size_t nX  = (size_t)Bm * Din;
    const size_t nH  = (size_t)Bm * Dh;

    const size_t need = 256 + 2 * (nW1 + nW2 + nX + nH);
    if (ws_size < need) return;

    uint8_t* ws = (uint8_t*)d_ws;
    unsigned int*   amax = (unsigned int*)ws;
    unsigned short* Q1 = (unsigned short*)(ws + 256);
    unsigned short* Q2 = Q1 + nW1;
    unsigned short* Xb = Q2 + nW2;
    char*           H  = (char*)(Xb + nX);     // H'-blocked bf16, nH*2 bytes

    init_amax<<<1, 64, 0, stream>>>(amax);
    absmax_kernel<<<1024, 256, 0, stream>>>((const float4*)W1, nW1 / 4, amax + 0);
    absmax_kernel<<<1024, 256, 0, stream>>>((const float4*)W2, nW2 / 4, amax + 1);
    quant_kernel<<<2048, 256, 0, stream>>>((const float4*)W1, nW1 / 4, amax + 0, (ushort4*)Q1);
    quant_kernel<<<2048, 256, 0, stream>>>((const float4*)W2, nW2 / 4, amax + 1, (ushort4*)Q2);
    cast_bf16_kernel<<<2048, 256, 0, stream>>>((const float4*)x, nX / 4, (ushort4*)Xb);

    // h = relu(scale1 * (x @ Q1^T) + b1) -> H'-blocked bf16
    gemm3<1, 0><<<dim3((Dh / 256) * (Bm / 256)), 512, 0, stream>>>(
        (const char*)Xb, Q1, b1, amax + 0, nullptr, H,
        /*N=*/Dh, /*K=*/Din, /*gx=*/Dh / 256, /*cw=*/16, /*NT=*/Din / 32);
    // y = scale2 * (h @ Q2^T) + b2 -> f32 row-major
    gemm3<0, 1><<<dim3((Dout / 256) * (Bm / 256)), 512, 0, stream>>>(
        H, Q2, b2, amax + 1, out, nullptr,
        /*N=*/Dout, /*K=*/Dh, /*gx=*/Dout / 256, /*cw=*/8, /*NT=*/Dh / 32);
}

// Round 12
// 534.073 us; speedup vs baseline: 1.0580x; 1.0490x over previous
//
#include <hip/hip_runtime.h>
#include <hip/hip_bf16.h>
#include <stdint.h>

typedef __attribute__((ext_vector_type(8))) short short8;
typedef __attribute__((ext_vector_type(4))) float f32x4;

#define AS1 __attribute__((address_space(1)))
#define AS3 __attribute__((address_space(3)))

// RNE float->bf16 (inputs are finite; no NaN handling needed)
static __device__ __forceinline__ unsigned short f2bf(float f) {
    unsigned int u = __float_as_uint(f);
    u += 0x7FFFu + ((u >> 16) & 1u);
    return (unsigned short)(u >> 16);
}

__global__ void init_amax(unsigned int* amax) {
    if (threadIdx.x < 2) amax[threadIdx.x] = 0u;
}

__global__ void absmax_kernel(const float4* __restrict__ w, size_t n4,
                              unsigned int* __restrict__ out) {
    float m = 0.0f;
    size_t i = (size_t)blockIdx.x * blockDim.x + threadIdx.x;
    size_t stride = (size_t)gridDim.x * blockDim.x;
    for (; i < n4; i += stride) {
        float4 v = w[i];
        m = fmaxf(m, fmaxf(fmaxf(fabsf(v.x), fabsf(v.y)),
                           fmaxf(fabsf(v.z), fabsf(v.w))));
    }
    #pragma unroll
    for (int off = 32; off > 0; off >>= 1)
        m = fmaxf(m, __shfl_down(m, off, 64));
    __shared__ float sm[4];
    int lane = threadIdx.x & 63, wid = threadIdx.x >> 6;
    if (lane == 0) sm[wid] = m;
    __syncthreads();
    if (threadIdx.x == 0) {
        float bm = fmaxf(fmaxf(sm[0], sm[1]), fmaxf(sm[2], sm[3]));
        atomicMax(out, __float_as_uint(bm));  // floats >=0: uint bit-compare monotone
    }
}

// FP4 E2M1 quantize to exact bf16 grid value (scale kept separate).
// idx = sum(a > mids[j]) matches np.searchsorted(mids, a, side='left').
static __device__ __forceinline__ unsigned short quant_one(float wv, float scale) {
    float a = fabsf(wv) / scale;
    int idx = (a > 0.25f) + (a > 0.75f) + (a > 1.25f) + (a > 1.75f)
            + (a > 2.5f)  + (a > 3.5f)  + (a > 5.0f);
    const unsigned long long lo = 0x3FC03F803F000000ull;  // bf16 bits {0,.5,1,1.5}
    const unsigned long long hi = 0x40C0408040404000ull;  // bf16 bits {2,3,4,6}
    unsigned long long tab = (idx < 4) ? lo : hi;
    unsigned short mag = (unsigned short)(tab >> ((idx & 3) * 16));
    unsigned short sgn = (unsigned short)((__float_as_uint(wv) >> 16) & 0x8000u);
    return (unsigned short)(mag | sgn);
}

__global__ void quant_kernel(const float4* __restrict__ w, size_t n4,
                             const unsigned int* __restrict__ amax,
                             ushort4* __restrict__ q) {
    const float scale = __uint_as_float(*amax) / 6.0f;
    size_t i = (size_t)blockIdx.x * blockDim.x + threadIdx.x;
    size_t stride = (size_t)gridDim.x * blockDim.x;
    for (; i < n4; i += stride) {
        float4 v = w[i];
        ushort4 o;
        o.x = quant_one(v.x, scale);
        o.y = quant_one(v.y, scale);
        o.z = quant_one(v.z, scale);
        o.w = quant_one(v.w, scale);
        q[i] = o;
    }
}

__global__ void cast_bf16_kernel(const float4* __restrict__ x, size_t n4,
                                 ushort4* __restrict__ o) {
    size_t i = (size_t)blockIdx.x * blockDim.x + threadIdx.x;
    size_t stride = (size_t)gridDim.x * blockDim.x;
    for (; i < n4; i += stride) {
        float4 v = x[i];
        ushort4 r;
        r.x = f2bf(v.x); r.y = f2bf(v.y); r.z = f2bf(v.z); r.w = f2bf(v.w);
        o[i] = r;
    }
}

// ========== 256x256 GEMM, BK=64, group-pipelined (R6 core, verified) ==========
// C[M][N] = A[M][K] (bf16) * B[N][K]^T (bf16), f32 acc.
// 512 thr = 8 waves (2M x 4N), per-wave 128x64, 2 K-tiles/iter.
// LDS 128KiB, buf by tile parity; per buf: A0@0 A1@16K B0@32K B1@48K.
// Subtile = 16 rows x 32 k (1024B); byte = swz(rin*64+kin*2), swz(x)=x^(((x>>9)&1)<<5).
// global_load_lds dest LINEAR; global source carries inverse swizzle.
//
// LAYA=1: A is the H'-BLOCKED internal layout (written by GEMM1's epilogue):
//   f(row,k) = (row>>4)*262144 + (k>>4)*512 + (row&3)*128 + ((row>>2)&3)*32 + (k&15)*2
// 16B of f = 8 consecutive k of one row -> drop-in for the A staging chunks.
// GEMM1 epilogue stores H' 128B-contiguous per instr (kills the 2x write amp).
// GEMM2 (f32 out) epilogue goes via LDS -> full-row 1KB coalesced stores.
//
// Register-capped at 8 waves/CU (acc 128 AGPR + ~100 VGPR ≈ 230/wave on the
// unified file): R10 (2 blocks/CU) and R11 (3-deep pipeline) both measured
// worse; this structure is the verified optimum of 6 variants (R2..R11).

#define GLL(gp, dst)                                                    \
    __builtin_amdgcn_global_load_lds((const AS1 unsigned int*)(gp),     \
        (AS3 unsigned int*)(dst), 16, 0, 0)

#define STGA(gp, ldsoff)                                        \
    do {                                                        \
        GLL((gp) + goffA0, lds + (ldsoff) + tid * 16);          \
        GLL((gp) + goffA1, lds + (ldsoff) + 8192 + tid * 16);   \
    } while (0)

#define STGB(gp, ldsoff)                                        \
    do {                                                        \
        GLL((gp) + goffB0, lds + (ldsoff) + tid * 16);          \
        GLL((gp) + goffB1, lds + (ldsoff) + 8192 + tid * 16);   \
    } while (0)

// byte advance for a k-offset of e ELEMENTS
#define KAB(e) ((size_t)(e) * (LAYA ? 32 : 2))
#define KBB(e) ((size_t)(e) * 2)

// 4 ds_read_b128: dst[i] = subtile (s0 + 2*i) of base
#define LD4(dst, base, s0)                                                    \
    do {                                                                      \
        _Pragma("unroll") for (int _i = 0; _i < 4; ++_i)                      \
            dst[_i] = *(const short8*)((base) + ((s0) + _i * 2) * 1024);      \
    } while (0)

// 16 MFMA: acc[AH*4 + i][j] += ARR[i] * BRR[j]
#define MFG(AH, ARR, BRR)                                                      \
    do {                                                                       \
        _Pragma("unroll") for (int _i = 0; _i < 4; ++_i)                       \
            _Pragma("unroll") for (int _j = 0; _j < 4; ++_j)                   \
                acc[(AH) * 4 + _i][_j] =                                       \
                    __builtin_amdgcn_mfma_f32_16x16x32_bf16(                   \
                        ARR[_i], BRR[_j], acc[(AH) * 4 + _i][_j], 0, 0, 0);    \
    } while (0)

#define BAR()  __builtin_amdgcn_s_barrier()
#define PRIO(x) __builtin_amdgcn_s_setprio(x)
#define SCHB() __builtin_amdgcn_sched_barrier(0)
#define LGKM(n) do { SCHB(); asm volatile("s_waitcnt lgkmcnt(" #n ")"); SCHB(); } while (0)

// One K-tile (R6-verified). VMODE: 2 = vmcnt(6), 1 = vmcnt(0), 0 = none.
#define KTILE(ldsB_, ldsA_, MA1, kA1, oA1, MORE, kNXT, oB0, oB1, oA0, VMODE)   \
    do {                                                                       \
        LD4(bE, ldsB_, 0);             /* B κ0: 4 reads */                     \
        LD4(aP, ldsA_, 0);             /* A h0 κ0: 4 */                        \
        LD4(aQ, ldsA_, 8);             /* A h1 κ0: 4 */                        \
        if (MA1) STGA(pA1 + KAB(kA1), oA1);                                    \
        LGKM(4);                       /* bE+aP ready, aQ in flight */         \
        PRIO(1); MFG(0, aP, bE); PRIO(0);                                      \
        LD4(bO, ldsB_, 1);             /* B κ1: 4 */                           \
        LD4(aP, ldsA_, 1);             /* A h0 κ1: 4 */                        \
        LGKM(8);                       /* aQ ready; bO,aP' in flight */        \
        PRIO(1); MFG(1, aQ, bE); PRIO(0);                                      \
        LD4(aQ, ldsA_, 9);             /* A h1 κ1: 4 */                        \
        LGKM(4);                       /* bO+aP' ready; aQ' in flight */       \
        PRIO(1); MFG(0, aP, bO); PRIO(0);                                      \
        LGKM(0);                       /* all 24 reads done -> buf free */     \
        BAR();                                                                 \
        if (MORE) { STGB(pB0 + KBB(kNXT), oB0); STGB(pB1 + KBB(kNXT), oB1);    \
                    STGA(pA0 + KAB(kNXT), oA0); }                              \
        SCHB();                                                                \
        PRIO(1); MFG(1, aQ, bO); PRIO(0);                                      \
        if (VMODE == 2) { asm volatile("s_waitcnt vmcnt(6)"); }                \
        if (VMODE == 1) { asm volatile("s_waitcnt vmcnt(0)"); }                \
        BAR();                                                                 \
    } while (0)

template <int RELU_BF16, int LAYA>
__global__ __launch_bounds__(512, 2)
void gemm8(const char* __restrict__ A,          // LAYA=0: row-major bf16; 1: H'-blocked
           const unsigned short* __restrict__ B,
           const float* __restrict__ bias,
           const unsigned int* __restrict__ amax,
           float* __restrict__ outF,            // RELU_BF16=0 dest (row-major f32)
           char* __restrict__ outH,             // RELU_BF16=1 dest (H'-blocked bf16)
           int M, int N, int K, int gx, int cw) {
    __shared__ __align__(16) char lds[131072];

    const int tid  = threadIdx.x;
    const int lane = tid & 63;
    const int wid  = tid >> 6;
    const int wm   = wid >> 2;   // 0..1: 128-row half
    const int wn   = wid & 3;    // 0..3: 64-col slice

    // 2D-chunked XCD mapping: XCD c gets a cw x (nc/cw) block-rect; bx fastest
    const int nwg = gridDim.x;
    const int wg  = blockIdx.x;
    const int c   = wg & 7;
    const int idx = wg >> 3;
    const int nc  = nwg >> 3;
    const int cxc = gx / cw;                 // chunks along x
    const int ox  = (c % cxc) * cw;
    const int oy  = (c / cxc) * (nc / cw);
    const int bx  = ox + idx % cw;
    const int by  = oy + idx / cw;
    const int col0 = bx * 256;
    const int row0 = by * 256;

    // per-lane swizzled ds_read byte offset within a 1024B subtile
    int sp = ((lane & 15) << 6) + ((lane >> 4) << 4);
    sp ^= ((sp >> 9) & 1) << 5;

    const char* ldsA_E = lds + wm * 16384 + sp;
    const char* ldsB_E = lds + 32768 + (wn >> 1) * 16384 + (wn & 1) * 8192 + sp;
    const char* ldsA_O = ldsA_E + 65536;
    const char* ldsB_O = ldsB_E + 65536;

    // stage source byte-offsets: LDS linear off o = l*8192 + tid*16 holds
    // element (row,k) = unswz(o); A offset per LAYA, B row-major.
    int goffA0, goffA1, goffB0, goffB1;
    {
        #pragma unroll
        for (int h = 0; h < 2; ++h) {
            int o = h * 8192 + tid * 16;
            int s = o >> 10, b = o & 1023;
            b ^= ((b >> 9) & 1) << 5;
            int row = ((s >> 1) << 4) + (b >> 6);
            int k   = ((s & 1) << 5) + ((b & 63) >> 1);
            int gB  = (row * K + k) * 2;
            int gA  = LAYA ? ((row >> 4) * 262144 + (k >> 4) * 512 +
                              (row & 3) * 128 + ((row >> 2) & 3) * 32 + (k & 15) * 2)
                           : gB;
            if (h == 0) { goffA0 = gA; goffB0 = gB; }
            else        { goffA1 = gA; goffB1 = gB; }
        }
    }
    const char* pA0 = A + (LAYA ? (size_t)row0 * 16384 : (size_t)row0 * K * 2);
    const char* pA1 = A + (LAYA ? (size_t)(row0 + 128) * 16384
                                : (size_t)(row0 + 128) * K * 2);
    const char* pB0 = (const char*)B + (size_t)col0 * K * 2;
    const char* pB1 = (const char*)B + (size_t)(col0 + 128) * K * 2;

    // prologue: tile0 [B0,B1,A0,A1] -> E; tile1 [B0,B1,A0] -> O
    STGB(pB0, 32768); STGB(pB1, 49152); STGA(pA0, 0); STGA(pA1, 16384);
    STGB(pB0 + KBB(64), 98304); STGB(pB1 + KBB(64), 114688);
    STGA(pA0 + KAB(64), 65536);
    asm volatile("s_waitcnt vmcnt(6)");   // tile0's 8 loads landed
    BAR();

    f32x4 acc[8][4] = {};
    short8 aP[4], aQ[4], bE[4], bO[4];
    const int NIT = K >> 7;

    for (int it = 0; it < NIT - 1; ++it) {
        const int o0 = it * 128;
        KTILE(ldsB_E, ldsA_E, 1, o0 + 64, 81920,
              1, o0 + 128, 32768, 49152, 0, 2);
        KTILE(ldsB_O, ldsA_O, 1, o0 + 128, 16384,
              1, o0 + 192, 98304, 114688, 65536, 2);
    }
    {
        const int o0 = (NIT - 1) * 128;   // peeled tail
        KTILE(ldsB_E, ldsA_E, 1, o0 + 64, 81920,
              0, 0, 0, 0, 0, 1);          // drain: vmcnt(0)
        KTILE(ldsB_O, ldsA_O, 0, 0, 0,
              0, 0, 0, 0, 0, 0);          // nothing outstanding
    }

    // acc C/D layout (verified m89/m91): col = lane&15, row = (lane>>4)*4 + r
    const float scale = __uint_as_float(*amax) / 6.0f;

    if (RELU_BF16) {
        // H'-blocked store: per (j,i,r) one 2B store, 64 lanes span 128B contiguous
        const int gbit = (lane >> 4) * 32 + (lane & 15) * 2;
        #pragma unroll
        for (int j = 0; j < 4; ++j) {
            const int col = col0 + wn * 64 + j * 16 + (lane & 15);
            const float bvv = bias[col];
            const size_t ktb = (size_t)((col0 >> 4) + wn * 4 + j) * 512;
            #pragma unroll
            for (int i = 0; i < 8; ++i) {
                const size_t rtb = (size_t)(((row0 + wm * 128) >> 4) + i) * 262144;
                #pragma unroll
                for (int r = 0; r < 4; ++r) {
                    float v = fmaxf(acc[i][j][r] * scale + bvv, 0.0f);
                    *(unsigned short*)(outH + rtb + ktb + r * 128 + gbit) = f2bf(v);
                }
            }
        }
    } else {
        // f32 out via LDS: 2 passes (wm groups); 16B-block XOR keyed on (row>>2)&3
        #pragma unroll
        for (int p = 0; p < 2; ++p) {
            if (wm == p) {
                #pragma unroll
                for (int j = 0; j < 4; ++j) {
                    const int colb = wn * 64 + j * 16 + (lane & 15);
                    const float bvv = bias[col0 + colb];
                    #pragma unroll
                    for (int i = 0; i < 8; ++i) {
                        #pragma unroll
                        for (int r = 0; r < 4; ++r) {
                            const int row_l = i * 16 + (lane >> 4) * 4 + r;
                            const int blk = (colb >> 2) ^ (((row_l >> 2) & 3) << 2);
                            *(float*)(lds + row_l * 1024 + blk * 16 + (colb & 3) * 4)
                                = acc[i][j][r] * scale + bvv;
                        }
                    }
                }
            }
            asm volatile("s_waitcnt lgkmcnt(0)");
            BAR();
            #pragma unroll
            for (int q = 0; q < 16; ++q) {
                const int flat  = q * 8192 + tid * 16;
                const int row_l = flat >> 10;
                const int blk0  = (flat >> 4) & 63;
                const int blk   = blk0 ^ (((row_l >> 2) & 3) << 2);
                f32x4 v = *(const f32x4*)(lds + row_l * 1024 + blk * 16);
                *(f32x4*)(outF + (size_t)(row0 + p * 128 + row_l) * N
                                 + col0 + blk0 * 4) = v;
            }
            BAR();
        }
    }
}

extern "C" void kernel_launch(void* const* d_in, const int* in_sizes, int n_in,
                              void* d_out, int out_size, void* d_ws, size_t ws_size,
                              hipStream_t stream) {
    const float* x  = (const float*)d_in[0];   // [8192, 2048]
    const float* W1 = (const float*)d_in[1];   // [8192, 2048]
    const float* b1 = (const float*)d_in[2];   // [8192]
    const float* W2 = (const float*)d_in[3];   // [2048, 8192]
    const float* b2 = (const float*)d_in[4];   // [2048]
    float* out = (float*)d_out;                // [8192, 2048] f32

    const int Bm = 8192, Din = 2048, Dh = 8192, Dout = 2048;
    const size_t nW1 = (size_t)Dh * Din;
    const size_t nW2 = (size_t)Dout * Dh;
    const size_t nX  = (size_t)Bm * Din;
    const size_t nH  = (size_t)Bm * Dh;

    const size_t need = 256 + 2 * (nW1 + nW2 + nX + nH);
    if (ws_size < need) return;

    uint8_t* ws = (uint8_t*)d_ws;
    unsigned int*   amax = (unsigned int*)ws;
    unsigned short* Q1 = (unsigned short*)(ws + 256);
    unsigned short* Q2 = Q1 + nW1;
    unsigned short* Xb = Q2 + nW2;
    char*           H  = (char*)(Xb + nX);     // H'-blocked bf16, nH*2 bytes

    init_amax<<<1, 64, 0, stream>>>(amax);
    absmax_kernel<<<1024, 256, 0, stream>>>((const float4*)W1, nW1 / 4, amax + 0);
    absmax_kernel<<<1024, 256, 0, stream>>>((const float4*)W2, nW2 / 4, amax + 1);
    quant_kernel<<<2048, 256, 0, stream>>>((const float4*)W1, nW1 / 4, amax + 0, (ushort4*)Q1);
    quant_kernel<<<2048, 256, 0, stream>>>((const float4*)W2, nW2 / 4, amax + 1, (ushort4*)Q2);
    cast_bf16_kernel<<<2048, 256, 0, stream>>>((const float4*)x, nX / 4, (ushort4*)Xb);

    // h = relu(scale1 * (x @ Q1^T) + b1) -> H' blocked bf16
    gemm8<1, 0><<<dim3((Dh / 256) * (Bm / 256)), 512, 0, stream>>>(
        (const char*)Xb, Q1, b1, amax + 0, nullptr, H,
        Bm, Dh, Din, /*gx=*/Dh / 256, /*cw=*/16);
    // y = scale2 * (h @ Q2^T) + b2 -> f32 row-major
    gemm8<0, 1><<<dim3((Dout / 256) * (Bm / 256)), 512, 0, stream>>>(
        H, Q2, b2, amax + 1, out, nullptr,
        Bm, Dout, Dh, /*gx=*/Dout / 256, /*cw=*/8);
}